// Round 8
// baseline (62.948 us; speedup 1.0000x reference)
//
#include <hip/hip_runtime.h>
#include <hip/hip_fp8.h>
#include <stdint.h>

#define MARGIN 0.3f
#define NROWS 4096
#define DIM   2048
#define BK    128                   // fp8 K-elements (= bytes) per tile row
#define NK    (DIM / BK)            // 16
// main kernel tiling: 64-row x 128-col blocks, upper triangle
#define BM    64
#define BN    128
#define NBJ   (NROWS / BN)          // 32
#define NBLK2 1056                  // sum_{bj<32} (2*bj+2), divisible by 8
// fallback tiling (128x128)
#define BT    128
#define NB    (NROWS / BT)          // 32
#define NBLK  (NB * (NB + 1) / 2)   // 528

typedef float f32x4 __attribute__((ext_vector_type(4)));
typedef int   i32x4 __attribute__((ext_vector_type(4)));
typedef int   i32x8 __attribute__((ext_vector_type(8)));
typedef short s16x8 __attribute__((ext_vector_type(8)));

__device__ __forceinline__ unsigned char f32_to_fp8(float f) {
  __hip_fp8_e4m3 h(f);                 // OCP e4m3fn on gfx950
  return (unsigned char)h.__x;
}

__device__ __forceinline__ ushort f32_to_bf16(float f) {
  uint32_t u = __float_as_uint(f);
  return (ushort)((u + 0x7FFFu + ((u >> 16) & 1u)) >> 16);
}

// async global->LDS, 16B per lane. LDS dest is wave-uniform base + lane*16
// (linear). The k-slot XOR swizzle is carried on the GLOBAL source address.
__device__ __forceinline__ void async_load16(const void* g, void* l) {
  __builtin_amdgcn_global_load_lds(
      (const __attribute__((address_space(1))) uint32_t*)g,
      (__attribute__((address_space(3))) uint32_t*)l, 16, 0, 0);
}

// ---------------------------------------------------------------------------
// prep: row L2-norm. FLY=0: write normalized fp8(e4m3) matrix. FLY=1: 1/norm.
// Also zeroes the accumulators.
// ---------------------------------------------------------------------------
template <int FLY>
__global__ __launch_bounds__(256) void prep_kernel(const float* __restrict__ in,
                                                   unsigned char* __restrict__ pn,
                                                   float* __restrict__ invn,
                                                   float* __restrict__ accum) {
  const int row = blockIdx.x;
  const int tid = threadIdx.x;
  if (row == 0 && tid == 0) { accum[0] = 0.f; accum[1] = 0.f; }

  const float4* rp = (const float4*)(in + (size_t)row * DIM);
  float4 v0 = rp[tid * 2];
  float4 v1 = rp[tid * 2 + 1];
  float ss = v0.x*v0.x + v0.y*v0.y + v0.z*v0.z + v0.w*v0.w
           + v1.x*v1.x + v1.y*v1.y + v1.z*v1.z + v1.w*v1.w;
  #pragma unroll
  for (int off = 32; off; off >>= 1) ss += __shfl_down(ss, off);

  __shared__ float wred[4];
  __shared__ float stot;
  const int lane = tid & 63, w = tid >> 6;
  if (lane == 0) wred[w] = ss;
  __syncthreads();
  if (tid == 0) stot = wred[0] + wred[1] + wred[2] + wred[3];
  __syncthreads();
  const float inv = 1.0f / fmaxf(sqrtf(stot), 1e-12f);

  if (FLY) {
    if (tid == 0) invn[row] = inv;
  } else {
    union { unsigned char b[8]; uint2 u; } pack;
    pack.b[0] = f32_to_fp8(v0.x * inv); pack.b[1] = f32_to_fp8(v0.y * inv);
    pack.b[2] = f32_to_fp8(v0.z * inv); pack.b[3] = f32_to_fp8(v0.w * inv);
    pack.b[4] = f32_to_fp8(v1.x * inv); pack.b[5] = f32_to_fp8(v1.y * inv);
    pack.b[6] = f32_to_fp8(v1.z * inv); pack.b[7] = f32_to_fp8(v1.w * inv);
    *(uint2*)(pn + (size_t)row * DIM + tid * 8) = pack.u;
  }
}

// ---------------------------------------------------------------------------
// tri_gemm: one block per 64x128 super-tile of sim = Pn Pn^T covering the
// upper triangle: row-block bi (64 rows), col-block bj (128 cols), kept iff
// bi <= 2*bj+1 (1056 blocks -> 4.1 blocks/CU, the m148 occupancy regime).
// 128 threads = 2 waves; wave w owns the 64x64 half [.., bj*128 + w*64).
// Per-output LDS traffic identical to the 128^2/64x64-wave config (64 B/out).
// fp8 e4m3 via mfma_scale_f32_16x16x128_f8f6f4, scales = 1.0 (0x7F).
// R6 loop structure (stage -> sync -> compute); inter-block overlap (m114)
// does the latency hiding now that ~4 independent blocks share each CU.
// ---------------------------------------------------------------------------
__global__ __launch_bounds__(128) void tri_gemm(const unsigned char* __restrict__ pn,
                                                float* __restrict__ accum) {
  // XCD-aware bijective swizzle (NBLK2 % 8 == 0)
  const int b = blockIdx.x;
  int t = (b & 7) * (NBLK2 / 8) + (b >> 3);
  // decode: col-block bj has (2*bj+2) row-blocks; cumulative bj^2+bj
  int bj = 0;
  while (t >= 2 * bj + 2) { t -= 2 * bj + 2; ++bj; }
  const int bi = t;                    // 0 .. 2*bj+1

  __shared__ __align__(16) unsigned char Asm[BM * BK];   //  8 KB
  __shared__ __align__(16) unsigned char Bsm[BN * BK];   // 16 KB

  const int tid  = threadIdx.x;
  const int lane = tid & 63;
  const int w    = tid >> 6;          // 0..1 : column half

  f32x4 acc[4][4] = {};
  const int rowA = bi * BM, rowB = bj * BN;

  // staging: 1 KB chunk = 8 rows x 128 B; lane l -> row +(l>>3), stored slot
  // (l&7); global true-k slot = (l&7) ^ (l>>3)
  const int srow  = (lane >> 3);
  const int gslot = (lane & 7) ^ srow;

  const unsigned char* gA = pn + (size_t)(rowA + srow) * DIM + gslot * 16;
  const unsigned char* gB = pn + (size_t)(rowB + srow) * DIM + gslot * 16;

  const int fr = lane & 15, g = lane >> 4;

  for (int k0 = 0; k0 < DIM; k0 += BK) {
    if (k0) __syncthreads();  // prior reads done before LDS overwrite
    // 24 chunks: 0-7 = A rows [8c,8c+8), 8-23 = B rows [8(c-8),+8).
    // wave w takes chunks c = 2q+w (12 each); branch is wave-uniform.
    #pragma unroll
    for (int q = 0; q < 12; ++q) {
      const int c = q * 2 + w;
      if (c < 8) {
        async_load16(gA + (size_t)(8 * c) * DIM + k0, Asm + (8 * c) * BK);
      } else {
        const int r = 8 * (c - 8);
        async_load16(gB + (size_t)r * DIM + k0, Bsm + r * BK);
      }
    }
    __syncthreads();  // drains vmcnt(0): global_load_lds data visible

    // fragments: lane -> row (l&15), k-group g=(l>>4); bytes [g*32,g*32+32)
    // = stored 16B slots (2g)^(row&7), (2g+1)^(row&7)
    i32x8 af[4], bfv[4];
    #pragma unroll
    for (int m = 0; m < 4; ++m) {
      const int ra = m * 16 + fr;
      const unsigned char* base = Asm + ra * BK;
      i32x4 lo = *(const i32x4*)(base + ((2 * g)     ^ (ra & 7)) * 16);
      i32x4 hi = *(const i32x4*)(base + ((2 * g + 1) ^ (ra & 7)) * 16);
      af[m] = __builtin_shufflevector(lo, hi, 0, 1, 2, 3, 4, 5, 6, 7);
    }
    #pragma unroll
    for (int n = 0; n < 4; ++n) {
      const int rb = w * 64 + n * 16 + fr;
      const unsigned char* base = Bsm + rb * BK;
      i32x4 lo = *(const i32x4*)(base + ((2 * g)     ^ (rb & 7)) * 16);
      i32x4 hi = *(const i32x4*)(base + ((2 * g + 1) ^ (rb & 7)) * 16);
      bfv[n] = __builtin_shufflevector(lo, hi, 0, 1, 2, 3, 4, 5, 6, 7);
    }

    #pragma unroll
    for (int m = 0; m < 4; ++m)
      #pragma unroll
      for (int n = 0; n < 4; ++n)
        acc[m][n] = __builtin_amdgcn_mfma_scale_f32_16x16x128_f8f6f4(
            af[m], bfv[n], acc[m][n],
            0, 0,                      // cbsz=fp8(e4m3), blgp=fp8(e4m3)
            0, 0x7F7F7F7F,             // scale_a: all e8m0 bytes = 1.0
            0, 0x7F7F7F7F);            // scale_b: all e8m0 bytes = 1.0
  }

  // ---- epilogue: mask + reduce (C/D layout is shape-determined) ----
  float lsum = 0.f, lcnt = 0.f;
  const int gib = rowA;
  const int gjb = rowB + w * 64;
  #pragma unroll
  for (int m = 0; m < 4; ++m) {
    #pragma unroll
    for (int n = 0; n < 4; ++n) {
      #pragma unroll
      for (int r = 0; r < 4; ++r) {
        int gi = gib + m * 16 + (lane >> 4) * 4 + r;
        int gj = gjb + n * 16 + (lane & 15);
        float s = acc[m][n][r];
        if (gi < gj && s > MARGIN) { lsum += s - MARGIN; lcnt += 1.f; }
      }
    }
  }
  #pragma unroll
  for (int off = 32; off; off >>= 1) {
    lsum += __shfl_down(lsum, off);
    lcnt += __shfl_down(lcnt, off);
  }
  __shared__ float rs[2], rc[2];
  if (lane == 0) { rs[w] = lsum; rc[w] = lcnt; }
  __syncthreads();
  if (tid == 0) {
    atomicAdd(&accum[0], rs[0] + rs[1]);
    atomicAdd(&accum[1], rc[0] + rc[1]);
  }
}

// ---------------------------------------------------------------------------
// Fallback (tiny workspace): bf16 on-the-fly convert, 256 threads / 4 waves,
// single-buffer, BK=64 bf16 (verified R2 structure), 128x128 tiles.
// ---------------------------------------------------------------------------
__global__ __launch_bounds__(256) void tri_gemm_fly(const float* __restrict__ inF,
                                                    const float* __restrict__ invn,
                                                    float* __restrict__ accum) {
  enum { FBK = 64 };
  int t = blockIdx.x, bi = 0;
  while (t >= NB - bi) { t -= NB - bi; ++bi; }
  const int bj = bi + t;

  __shared__ __align__(16) ushort Asm[BT * FBK];
  __shared__ __align__(16) ushort Bsm[BT * FBK];

  const int tid  = threadIdx.x;
  const int lane = tid & 63;
  const int w    = tid >> 6;
  const int wr   = w >> 1, wc = w & 1;

  f32x4 acc[4][4] = {};
  const int rowA = bi * BT, rowB = bj * BT;

  for (int k0 = 0; k0 < DIM; k0 += FBK) {
    if (k0) __syncthreads();
    #pragma unroll
    for (int p = 0; p < 8; ++p) {
      int c   = p * 256 + tid;
      int isB = c >> 10;
      int cc  = c & 1023;
      int r   = cc >> 3;
      int s   = cc & 7;
      const int grow = (isB ? rowB : rowA) + r;
      const float4* src = (const float4*)(inF + (size_t)grow * DIM + k0 + s * 8);
      float4 v0 = src[0], v1 = src[1];
      int4 pack;
      ushort* h = (ushort*)&pack;
      h[0] = f32_to_bf16(v0.x); h[1] = f32_to_bf16(v0.y);
      h[2] = f32_to_bf16(v0.z); h[3] = f32_to_bf16(v0.w);
      h[4] = f32_to_bf16(v1.x); h[5] = f32_to_bf16(v1.y);
      h[6] = f32_to_bf16(v1.z); h[7] = f32_to_bf16(v1.w);
      *(int4*)((isB ? Bsm : Asm) + r * FBK + (s ^ (r & 7)) * 8) = pack;
    }
    __syncthreads();

    s16x8 af[2][4], bfv[2][4];
    const int fr = lane & 15, hi = lane >> 4;
    #pragma unroll
    for (int kk = 0; kk < 2; ++kk)
      #pragma unroll
      for (int m = 0; m < 4; ++m) {
        const int ra = wr * 64 + m * 16 + fr;
        af[kk][m] = *(const s16x8*)(Asm + ra * FBK + ((kk * 4 + hi) ^ (ra & 7)) * 8);
        const int rb = wc * 64 + m * 16 + fr;
        bfv[kk][m] = *(const s16x8*)(Bsm + rb * FBK + ((kk * 4 + hi) ^ (rb & 7)) * 8);
      }
    #pragma unroll
    for (int kk = 0; kk < 2; ++kk)
      #pragma unroll
      for (int m = 0; m < 4; ++m)
        #pragma unroll
        for (int n = 0; n < 4; ++n)
          acc[m][n] = __builtin_amdgcn_mfma_f32_16x16x32_bf16(af[kk][m], bfv[kk][n],
                                                              acc[m][n], 0, 0, 0);
  }

  float lsum = 0.f, lcnt = 0.f;
  const int gib = rowA + wr * 64;
  const int gjb = rowB + wc * 64;
  #pragma unroll
  for (int m = 0; m < 4; ++m)
    #pragma unroll
    for (int n = 0; n < 4; ++n)
      #pragma unroll
      for (int r = 0; r < 4; ++r) {
        int gi = gib + m * 16 + (lane >> 4) * 4 + r;
        int gj = gjb + n * 16 + (lane & 15);
        float s = acc[m][n][r] * invn[gi] * invn[gj];
        if (gi < gj && s > MARGIN) { lsum += s - MARGIN; lcnt += 1.f; }
      }
  #pragma unroll
  for (int off = 32; off; off >>= 1) {
    lsum += __shfl_down(lsum, off);
    lcnt += __shfl_down(lcnt, off);
  }
  __shared__ float rs[4], rc[4];
  if (lane == 0) { rs[w] = lsum; rc[w] = lcnt; }
  __syncthreads();
  if (tid == 0) {
    atomicAdd(&accum[0], rs[0] + rs[1] + rs[2] + rs[3]);
    atomicAdd(&accum[1], rc[0] + rc[1] + rc[2] + rc[3]);
  }
}

__global__ void finalize_kernel(const float* __restrict__ accum, float* __restrict__ out) {
  if (threadIdx.x == 0) out[0] = (accum[1] < 0.5f) ? 0.0f : accum[0] / accum[1];
}

extern "C" void kernel_launch(void* const* d_in, const int* in_sizes, int n_in,
                              void* d_out, int out_size, void* d_ws, size_t ws_size,
                              hipStream_t stream) {
  const float* in = (const float*)d_in[0];
  float* out = (float*)d_out;
  const size_t pn_bytes = (size_t)NROWS * DIM;   // fp8: 8.4 MB

  if (ws_size >= pn_bytes + 2 * sizeof(float)) {
    unsigned char* pn = (unsigned char*)d_ws;
    float* accum = (float*)((char*)d_ws + pn_bytes);
    prep_kernel<0><<<NROWS, 256, 0, stream>>>(in, pn, nullptr, accum);
    tri_gemm<<<NBLK2, 128, 0, stream>>>(pn, accum);
    finalize_kernel<<<1, 64, 0, stream>>>(accum, out);
  } else {
    float* invn  = (float*)d_ws;
    float* accum = (float*)((char*)d_ws + NROWS * sizeof(float));
    prep_kernel<1><<<NROWS, 256, 0, stream>>>(in, nullptr, invn, accum);
    tri_gemm_fly<<<NBLK, 256, 0, stream>>>(in, invn, accum);
    finalize_kernel<<<1, 64, 0, stream>>>(accum, out);
  }
}

// Round 9
// 41.321 us; speedup vs baseline: 1.5234x; 1.5234x over previous
//
#include <hip/hip_runtime.h>
#include <stdint.h>

#define MARGIN 0.3f
#define NROWS 4096
#define DIM   2048
#define ROWB  1024                  // fp4: DIM/2 bytes per row
#define BT    128
#define NKS   16                    // K-steps of 128 elements
#define NB    (NROWS / BT)          // 32
#define NBLK  (NB * (NB + 1) / 2)   // 528 (divisible by 8 -> clean XCD swizzle)

typedef float f32x4 __attribute__((ext_vector_type(4)));
typedef int   i32x4 __attribute__((ext_vector_type(4)));
typedef int   i32x8 __attribute__((ext_vector_type(8)));
typedef short s16x8 __attribute__((ext_vector_type(8)));

__device__ __forceinline__ ushort f32_to_bf16(float f) {
  uint32_t u = __float_as_uint(f);
  return (ushort)((u + 0x7FFFu + ((u >> 16) & 1u)) >> 16);
}

// e2m1 quantizer, RNE to grid {0,.5,1,1.5,2,3,4,6}, clamp at 6.
__device__ __forceinline__ unsigned f32_to_fp4(float y) {
  unsigned s = (__float_as_uint(y) >> 31) << 3;
  float a = fabsf(y);
  unsigned c;
  if      (a < 0.25f) c = 0;
  else if (a < 0.75f) c = 1;
  else if (a < 1.25f) c = 2;
  else if (a < 1.75f) c = 3;
  else if (a < 2.5f)  c = 4;
  else if (a < 3.5f)  c = 5;
  else if (a < 5.0f)  c = 6;
  else                c = 7;
  return s | c;
}

// async global->LDS, 16B per lane. LDS dest is wave-uniform base + lane*16
// (linear). Swizzle is carried on the GLOBAL source address.
__device__ __forceinline__ void async_load16(const void* g, void* l) {
  __builtin_amdgcn_global_load_lds(
      (const __attribute__((address_space(1))) uint32_t*)g,
      (__attribute__((address_space(3))) uint32_t*)l, 16, 0, 0);
}

// ---------------------------------------------------------------------------
// prep: row L2-norm. FLY=0: write normalized fp4(e2m1) matrix at scale 2^6
// (value = fp4 * 2^-6 via MFMA scale operand). FLY=1: write 1/norm.
// Also zeroes the accumulators.
// ---------------------------------------------------------------------------
template <int FLY>
__global__ __launch_bounds__(256) void prep_kernel(const float* __restrict__ in,
                                                   unsigned char* __restrict__ pn,
                                                   float* __restrict__ invn,
                                                   float* __restrict__ accum) {
  const int row = blockIdx.x;
  const int tid = threadIdx.x;
  if (row == 0 && tid == 0) { accum[0] = 0.f; accum[1] = 0.f; }

  const float4* rp = (const float4*)(in + (size_t)row * DIM);
  float4 v0 = rp[tid * 2];
  float4 v1 = rp[tid * 2 + 1];
  float ss = v0.x*v0.x + v0.y*v0.y + v0.z*v0.z + v0.w*v0.w
           + v1.x*v1.x + v1.y*v1.y + v1.z*v1.z + v1.w*v1.w;
  #pragma unroll
  for (int off = 32; off; off >>= 1) ss += __shfl_down(ss, off);

  __shared__ float wred[4];
  __shared__ float stot;
  const int lane = tid & 63, w = tid >> 6;
  if (lane == 0) wred[w] = ss;
  __syncthreads();
  if (tid == 0) stot = wred[0] + wred[1] + wred[2] + wred[3];
  __syncthreads();
  const float inv = 1.0f / fmaxf(sqrtf(stot), 1e-12f);

  if (FLY) {
    if (tid == 0) invn[row] = inv;
  } else {
    const float sc = inv * 64.0f;            // pre-scale by 2^6
    float e[8] = {v0.x, v0.y, v0.z, v0.w, v1.x, v1.y, v1.z, v1.w};
    uint32_t u = 0;
    #pragma unroll
    for (int j = 0; j < 4; ++j) {
      unsigned lo = f32_to_fp4(e[2*j]   * sc);
      unsigned hi = f32_to_fp4(e[2*j+1] * sc);
      u |= (lo | (hi << 4)) << (8 * j);
    }
    *(uint32_t*)(pn + (size_t)row * ROWB + tid * 4) = u;
  }
}

// ---------------------------------------------------------------------------
// tri_gemm: one block per upper-triangular 128x128 super-tile of sim = Pn Pn^T.
// fp4 e2m1 via mfma_scale_f32_16x16x128_f8f6f4 (cbsz=blgp=4), scale bytes
// 0x79 = 2^-6 on both operands -> acc = sim directly.
// 256 threads = 4 waves (2x2), wave tile 64x64 (4x4 frags), 16 K-steps.
// LDS layout: 2 matrix rows pair-packed per 128-B LDS row (64 LDS rows per
// panel = 8 KB each); 16B slot XOR 'g ^ ((mrow>>1)&3)' -> per-16-lane reads
// are 2-way banked (free, same criterion as the verified R2 bf16 layout).
// Staging: global_load_lds 16B/lane, linear LDS dest; the pair-pack + slot
// swizzle are carried on the GLOBAL source address.
// One ds_read_b128 per fragment (fp4 K=128 = 16B/lane, hi regs unused).
// ---------------------------------------------------------------------------
__global__ __launch_bounds__(256) void tri_gemm(const unsigned char* __restrict__ pn,
                                                float* __restrict__ accum) {
  // XCD-aware bijective swizzle (NBLK % 8 == 0)
  const int b = blockIdx.x;
  int t = (b & 7) * (NBLK / 8) + (b >> 3);
  int bi = 0;
  while (t >= NB - bi) { t -= NB - bi; ++bi; }
  const int bj = bi + t;

  __shared__ __align__(16) unsigned char Asm[64 * 128];   // 8 KB (128 mrows)
  __shared__ __align__(16) unsigned char Bsm[64 * 128];   // 8 KB

  const int tid  = threadIdx.x;
  const int lane = tid & 63;
  const int w    = tid >> 6;          // 0..3
  const int wr   = w >> 1;            // 0..1
  const int wc   = w & 1;             // 0..1

  f32x4 acc[4][4] = {};
  const int rowA = bi * BT, rowB = bj * BT;

  // staging lane map within a 1-KB chunk (= 16 mrows): lane l -> LDS byte
  // l*16: LDS-row q=(l>>3), mrow parity p=(l>>2)&1, stored slot s=(l&3).
  // stored slot s holds true kslot s ^ (q&3)  [q&3 == (l>>3)&3]
  const int srow2 = 2 * (lane >> 3) + ((lane >> 2) & 1);
  const int kslot = (lane & 3) ^ ((lane >> 3) & 3);

  const unsigned char* gA = pn + (size_t)(rowA + srow2) * ROWB + kslot * 16;
  const unsigned char* gB = pn + (size_t)(rowB + srow2) * ROWB + kslot * 16;

  const int fr = lane & 15, g = lane >> 4;

  for (int ks = 0; ks < NKS; ++ks) {
    const int kb = ks * 64;           // 128 elems = 64 fp4 bytes per row
    if (ks) __syncthreads();          // prior reads done before overwrite
    // 8 A-chunks + 8 B-chunks of 1 KB (16 mrows each); wave w: chunks w, w+4
    #pragma unroll
    for (int h = 0; h < 2; ++h) {
      const int c = w + h * 4;
      async_load16(gA + (size_t)c * (16 * ROWB) + kb, Asm + c * 1024);
      async_load16(gB + (size_t)c * (16 * ROWB) + kb, Bsm + c * 1024);
    }
    __syncthreads();                  // vmcnt(0) drain: data visible

    // fragment: mrow r, true kgroup g -> LDS byte
    // (r>>1)*128 + (r&1)*64 + (g ^ ((r>>1)&3))*16, single ds_read_b128
    const i32x4 z4 = {0, 0, 0, 0};
    i32x8 af[4], bf[4];
    #pragma unroll
    for (int m = 0; m < 4; ++m) {
      const int ra = wr * 64 + m * 16 + fr;
      i32x4 va = *(const i32x4*)(Asm + (ra >> 1) * 128 + (ra & 1) * 64 +
                                 ((g ^ ((ra >> 1) & 3)) * 16));
      af[m] = __builtin_shufflevector(va, z4, 0, 1, 2, 3, 4, 5, 6, 7);
      const int rb = wc * 64 + m * 16 + fr;
      i32x4 vb = *(const i32x4*)(Bsm + (rb >> 1) * 128 + (rb & 1) * 64 +
                                 ((g ^ ((rb >> 1) & 3)) * 16));
      bf[m] = __builtin_shufflevector(vb, z4, 0, 1, 2, 3, 4, 5, 6, 7);
    }

    #pragma unroll
    for (int m = 0; m < 4; ++m)
      #pragma unroll
      for (int n = 0; n < 4; ++n)
        acc[m][n] = __builtin_amdgcn_mfma_scale_f32_16x16x128_f8f6f4(
            af[m], bf[n], acc[m][n],
            4, 4,                      // cbsz=fp4(e2m1), blgp=fp4(e2m1)
            0, 0x79797979,             // scale_a: e8m0 = 2^-6 everywhere
            0, 0x79797979);            // scale_b: e8m0 = 2^-6 everywhere
  }

  // ---- epilogue: mask + reduce (C/D layout is shape-determined) ----
  float lsum = 0.f, lcnt = 0.f;
  const int gib = rowA + wr * 64;
  const int gjb = rowB + wc * 64;
  #pragma unroll
  for (int m = 0; m < 4; ++m) {
    #pragma unroll
    for (int n = 0; n < 4; ++n) {
      #pragma unroll
      for (int r = 0; r < 4; ++r) {
        int gi = gib + m * 16 + (lane >> 4) * 4 + r;
        int gj = gjb + n * 16 + (lane & 15);
        float s = acc[m][n][r];
        if (gi < gj && s > MARGIN) { lsum += s - MARGIN; lcnt += 1.f; }
      }
    }
  }
  #pragma unroll
  for (int off = 32; off; off >>= 1) {
    lsum += __shfl_down(lsum, off);
    lcnt += __shfl_down(lcnt, off);
  }
  __shared__ float rs[4], rc[4];
  if (lane == 0) { rs[w] = lsum; rc[w] = lcnt; }
  __syncthreads();
  if (tid == 0) {
    atomicAdd(&accum[0], rs[0] + rs[1] + rs[2] + rs[3]);
    atomicAdd(&accum[1], rc[0] + rc[1] + rc[2] + rc[3]);
  }
}

// ---------------------------------------------------------------------------
// Fallback (tiny workspace): bf16 on-the-fly convert, 256 threads / 4 waves,
// single-buffer, BK=64 bf16 (verified R2 structure), 128x128 tiles.
// ---------------------------------------------------------------------------
__global__ __launch_bounds__(256) void tri_gemm_fly(const float* __restrict__ inF,
                                                    const float* __restrict__ invn,
                                                    float* __restrict__ accum) {
  enum { FBK = 64 };
  int t = blockIdx.x, bi = 0;
  while (t >= NB - bi) { t -= NB - bi; ++bi; }
  const int bj = bi + t;

  __shared__ __align__(16) ushort Asm[BT * FBK];
  __shared__ __align__(16) ushort Bsm[BT * FBK];

  const int tid  = threadIdx.x;
  const int lane = tid & 63;
  const int w    = tid >> 6;
  const int wr   = w >> 1, wc = w & 1;

  f32x4 acc[4][4] = {};
  const int rowA = bi * BT, rowB = bj * BT;

  for (int k0 = 0; k0 < DIM; k0 += FBK) {
    if (k0) __syncthreads();
    #pragma unroll
    for (int p = 0; p < 8; ++p) {
      int c   = p * 256 + tid;
      int isB = c >> 10;
      int cc  = c & 1023;
      int r   = cc >> 3;
      int s   = cc & 7;
      const int grow = (isB ? rowB : rowA) + r;
      const float4* src = (const float4*)(inF + (size_t)grow * DIM + k0 + s * 8);
      float4 v0 = src[0], v1 = src[1];
      int4 pack;
      ushort* h = (ushort*)&pack;
      h[0] = f32_to_bf16(v0.x); h[1] = f32_to_bf16(v0.y);
      h[2] = f32_to_bf16(v0.z); h[3] = f32_to_bf16(v0.w);
      h[4] = f32_to_bf16(v1.x); h[5] = f32_to_bf16(v1.y);
      h[6] = f32_to_bf16(v1.z); h[7] = f32_to_bf16(v1.w);
      *(int4*)((isB ? Bsm : Asm) + r * FBK + (s ^ (r & 7)) * 8) = pack;
    }
    __syncthreads();

    s16x8 af[2][4], bfv[2][4];
    const int fr = lane & 15, hi = lane >> 4;
    #pragma unroll
    for (int kk = 0; kk < 2; ++kk)
      #pragma unroll
      for (int m = 0; m < 4; ++m) {
        const int ra = wr * 64 + m * 16 + fr;
        af[kk][m] = *(const s16x8*)(Asm + ra * FBK + ((kk * 4 + hi) ^ (ra & 7)) * 8);
        const int rb = wc * 64 + m * 16 + fr;
        bfv[kk][m] = *(const s16x8*)(Bsm + rb * FBK + ((kk * 4 + hi) ^ (rb & 7)) * 8);
      }
    #pragma unroll
    for (int kk = 0; kk < 2; ++kk)
      #pragma unroll
      for (int m = 0; m < 4; ++m)
        #pragma unroll
        for (int n = 0; n < 4; ++n)
          acc[m][n] = __builtin_amdgcn_mfma_f32_16x16x32_bf16(af[kk][m], bfv[kk][n],
                                                              acc[m][n], 0, 0, 0);
  }

  float lsum = 0.f, lcnt = 0.f;
  const int gib = rowA + wr * 64;
  const int gjb = rowB + wc * 64;
  #pragma unroll
  for (int m = 0; m < 4; ++m)
    #pragma unroll
    for (int n = 0; n < 4; ++n)
      #pragma unroll
      for (int r = 0; r < 4; ++r) {
        int gi = gib + m * 16 + (lane >> 4) * 4 + r;
        int gj = gjb + n * 16 + (lane & 15);
        float s = acc[m][n][r] * invn[gi] * invn[gj];
        if (gi < gj && s > MARGIN) { lsum += s - MARGIN; lcnt += 1.f; }
      }
  #pragma unroll
  for (int off = 32; off; off >>= 1) {
    lsum += __shfl_down(lsum, off);
    lcnt += __shfl_down(lcnt, off);
  }
  __shared__ float rs[4], rc[4];
  if (lane == 0) { rs[w] = lsum; rc[w] = lcnt; }
  __syncthreads();
  if (tid == 0) {
    atomicAdd(&accum[0], rs[0] + rs[1] + rs[2] + rs[3]);
    atomicAdd(&accum[1], rc[0] + rc[1] + rc[2] + rc[3]);
  }
}

__global__ void finalize_kernel(const float* __restrict__ accum, float* __restrict__ out) {
  if (threadIdx.x == 0) out[0] = (accum[1] < 0.5f) ? 0.0f : accum[0] / accum[1];
}

extern "C" void kernel_launch(void* const* d_in, const int* in_sizes, int n_in,
                              void* d_out, int out_size, void* d_ws, size_t ws_size,
                              hipStream_t stream) {
  const float* in = (const float*)d_in[0];
  float* out = (float*)d_out;
  const size_t pn_bytes = (size_t)NROWS * ROWB;   // fp4: 4.2 MB

  if (ws_size >= pn_bytes + 2 * sizeof(float)) {
    unsigned char* pn = (unsigned char*)d_ws;
    float* accum = (float*)((char*)d_ws + pn_bytes);
    prep_kernel<0><<<NROWS, 256, 0, stream>>>(in, pn, nullptr, accum);
    tri_gemm<<<NBLK, 256, 0, stream>>>(pn, accum);
    finalize_kernel<<<1, 64, 0, stream>>>(accum, out);
  } else {
    float* invn  = (float*)d_ws;
    float* accum = (float*)((char*)d_ws + NROWS * sizeof(float));
    prep_kernel<1><<<NROWS, 256, 0, stream>>>(in, nullptr, invn, accum);
    tri_gemm_fly<<<NBLK, 256, 0, stream>>>(in, invn, accum);
    finalize_kernel<<<1, 64, 0, stream>>>(accum, out);
  }
}

// Round 10
// 39.566 us; speedup vs baseline: 1.5910x; 1.0443x over previous
//
#include <hip/hip_runtime.h>
#include <stdint.h>

#define MARGIN 0.3f
#define NROWS 4096
#define DIM   2048
#define ROWB  1024                  // fp4: DIM/2 bytes per row
#define BT    128
#define BKB   128                   // bytes per row per K-step (256 elements)
#define NKS   (ROWB / BKB)          // 8 K-steps
#define NB    (NROWS / BT)          // 32
#define NBLK  (NB * (NB + 1) / 2)   // 528 (divisible by 8 -> clean XCD swizzle)

typedef float f32x4 __attribute__((ext_vector_type(4)));
typedef int   i32x4 __attribute__((ext_vector_type(4)));
typedef int   i32x8 __attribute__((ext_vector_type(8)));
typedef short s16x8 __attribute__((ext_vector_type(8)));

__device__ __forceinline__ ushort f32_to_bf16(float f) {
  uint32_t u = __float_as_uint(f);
  return (ushort)((u + 0x7FFFu + ((u >> 16) & 1u)) >> 16);
}

// e2m1 quantizer, RNE to grid {0,.5,1,1.5,2,3,4,6}, clamp at 6.
__device__ __forceinline__ unsigned f32_to_fp4(float y) {
  unsigned s = (__float_as_uint(y) >> 31) << 3;
  float a = fabsf(y);
  unsigned c;
  if      (a < 0.25f) c = 0;
  else if (a < 0.75f) c = 1;
  else if (a < 1.25f) c = 2;
  else if (a < 1.75f) c = 3;
  else if (a < 2.5f)  c = 4;
  else if (a < 3.5f)  c = 5;
  else if (a < 5.0f)  c = 6;
  else                c = 7;
  return s | c;
}

// async global->LDS, 16B per lane. LDS dest is wave-uniform base + lane*16
// (linear). Swizzle is carried on the GLOBAL source address.
__device__ __forceinline__ void async_load16(const void* g, void* l) {
  __builtin_amdgcn_global_load_lds(
      (const __attribute__((address_space(1))) uint32_t*)g,
      (__attribute__((address_space(3))) uint32_t*)l, 16, 0, 0);
}

// ---------------------------------------------------------------------------
// prep: row L2-norm. FLY=0: write normalized fp4(e2m1) matrix at scale 2^6
// (value = fp4 * 2^-6 via MFMA scale operand). FLY=1: write 1/norm.
// Also zeroes the accumulators.
// ---------------------------------------------------------------------------
template <int FLY>
__global__ __launch_bounds__(256) void prep_kernel(const float* __restrict__ in,
                                                   unsigned char* __restrict__ pn,
                                                   float* __restrict__ invn,
                                                   float* __restrict__ accum) {
  const int row = blockIdx.x;
  const int tid = threadIdx.x;
  if (row == 0 && tid == 0) { accum[0] = 0.f; accum[1] = 0.f; }

  const float4* rp = (const float4*)(in + (size_t)row * DIM);
  float4 v0 = rp[tid * 2];
  float4 v1 = rp[tid * 2 + 1];
  float ss = v0.x*v0.x + v0.y*v0.y + v0.z*v0.z + v0.w*v0.w
           + v1.x*v1.x + v1.y*v1.y + v1.z*v1.z + v1.w*v1.w;
  #pragma unroll
  for (int off = 32; off; off >>= 1) ss += __shfl_down(ss, off);

  __shared__ float wred[4];
  __shared__ float stot;
  const int lane = tid & 63, w = tid >> 6;
  if (lane == 0) wred[w] = ss;
  __syncthreads();
  if (tid == 0) stot = wred[0] + wred[1] + wred[2] + wred[3];
  __syncthreads();
  const float inv = 1.0f / fmaxf(sqrtf(stot), 1e-12f);

  if (FLY) {
    if (tid == 0) invn[row] = inv;
  } else {
    const float sc = inv * 64.0f;            // pre-scale by 2^6
    float e[8] = {v0.x, v0.y, v0.z, v0.w, v1.x, v1.y, v1.z, v1.w};
    uint32_t u = 0;
    #pragma unroll
    for (int j = 0; j < 4; ++j) {
      unsigned lo = f32_to_fp4(e[2*j]   * sc);
      unsigned hi = f32_to_fp4(e[2*j+1] * sc);
      u |= (lo | (hi << 4)) << (8 * j);
    }
    *(uint32_t*)(pn + (size_t)row * ROWB + tid * 4) = u;
  }
}

// ---------------------------------------------------------------------------
// tri_gemm: one block per upper-triangular 128x128 super-tile of sim = Pn Pn^T.
// fp4 e2m1 via mfma_scale_f32_16x16x128_f8f6f4 (cbsz=blgp=4), scale bytes
// 0x79 = 2^-6 on both operands -> acc = sim directly.
// 256 threads = 4 waves (2x2), wave tile 64x64 (4x4 frags).
// BK = 256 elements = 128 B/row/step -> NKS = 8 K-steps (halved from R9's 16:
// R6 vs R9 showed time/step is a FIXED latency chain, so step count is the
// lever). LDS: per panel 128 rows x 128 B = 16 KB; 8-slot x 16B row with the
// R2-verified slot XOR (slot ^ (row&7)) -> conflict-free b128 reads.
// Staging: global_load_lds 16B/lane, linear LDS dest, swizzle on the GLOBAL
// source address. Fragments loaded just-in-time per sub-K (kk=0,1) to cap
// VGPR; one ds_read_b128 per fragment.
// ---------------------------------------------------------------------------
__global__ __launch_bounds__(256) void tri_gemm(const unsigned char* __restrict__ pn,
                                                float* __restrict__ accum) {
  // XCD-aware bijective swizzle (NBLK % 8 == 0)
  const int b = blockIdx.x;
  int t = (b & 7) * (NBLK / 8) + (b >> 3);
  int bi = 0;
  while (t >= NB - bi) { t -= NB - bi; ++bi; }
  const int bj = bi + t;

  __shared__ __align__(16) unsigned char Asm[BT * BKB];   // 16 KB
  __shared__ __align__(16) unsigned char Bsm[BT * BKB];   // 16 KB

  const int tid  = threadIdx.x;
  const int lane = tid & 63;
  const int w    = tid >> 6;          // 0..3
  const int wr   = w >> 1;            // 0..1
  const int wc   = w & 1;             // 0..1

  f32x4 acc[4][4] = {};
  const int rowA = bi * BT, rowB = bj * BT;

  // staging: 1 KB chunk = 8 rows x 128 B; lane l -> row +(l>>3), stored slot
  // (l&7); global true-k slot = (l&7) ^ (l>>3)   [row&7 == l>>3]
  const int srow  = (lane >> 3);
  const int gslot = (lane & 7) ^ srow;

  const unsigned char* gA = pn + (size_t)(rowA + srow) * ROWB + gslot * 16;
  const unsigned char* gB = pn + (size_t)(rowB + srow) * ROWB + gslot * 16;

  const int fr = lane & 15, g = lane >> 4;
  const i32x4 z4 = {0, 0, 0, 0};

  for (int ks = 0; ks < NKS; ++ks) {
    const int kb = ks * BKB;          // byte offset within row
    if (ks) __syncthreads();          // prior reads done before overwrite
    #pragma unroll
    for (int q = 0; q < 4; ++q) {
      const int r = w * 32 + q * 8;   // chunk base row (multiple of 8)
      async_load16(gA + (size_t)r * ROWB + kb, Asm + r * BKB);
      async_load16(gB + (size_t)r * ROWB + kb, Bsm + r * BKB);
    }
    __syncthreads();                  // vmcnt(0) drain: data visible

    // sub-K kk covers true k-bytes [kk*64, kk*64+64); lane's 16B for kgroup g
    // sits at stored slot (kk*4 + g) ^ (row&7). One ds_read_b128 each.
    #pragma unroll
    for (int kk = 0; kk < 2; ++kk) {
      i32x8 af[4], bf[4];
      #pragma unroll
      for (int m = 0; m < 4; ++m) {
        const int ra = wr * 64 + m * 16 + fr;
        i32x4 va = *(const i32x4*)(Asm + ra * BKB + (((kk * 4 + g) ^ (ra & 7)) * 16));
        af[m] = __builtin_shufflevector(va, z4, 0, 1, 2, 3, 4, 5, 6, 7);
        const int rb = wc * 64 + m * 16 + fr;
        i32x4 vb = *(const i32x4*)(Bsm + rb * BKB + (((kk * 4 + g) ^ (rb & 7)) * 16));
        bf[m] = __builtin_shufflevector(vb, z4, 0, 1, 2, 3, 4, 5, 6, 7);
      }
      #pragma unroll
      for (int m = 0; m < 4; ++m)
        #pragma unroll
        for (int n = 0; n < 4; ++n)
          acc[m][n] = __builtin_amdgcn_mfma_scale_f32_16x16x128_f8f6f4(
              af[m], bf[n], acc[m][n],
              4, 4,                      // cbsz=fp4(e2m1), blgp=fp4(e2m1)
              0, 0x79797979,             // scale_a: e8m0 = 2^-6 everywhere
              0, 0x79797979);            // scale_b: e8m0 = 2^-6 everywhere
    }
  }

  // ---- epilogue: mask + reduce (C/D layout is shape-determined) ----
  float lsum = 0.f, lcnt = 0.f;
  const int gib = rowA + wr * 64;
  const int gjb = rowB + wc * 64;
  #pragma unroll
  for (int m = 0; m < 4; ++m) {
    #pragma unroll
    for (int n = 0; n < 4; ++n) {
      #pragma unroll
      for (int r = 0; r < 4; ++r) {
        int gi = gib + m * 16 + (lane >> 4) * 4 + r;
        int gj = gjb + n * 16 + (lane & 15);
        float s = acc[m][n][r];
        if (gi < gj && s > MARGIN) { lsum += s - MARGIN; lcnt += 1.f; }
      }
    }
  }
  #pragma unroll
  for (int off = 32; off; off >>= 1) {
    lsum += __shfl_down(lsum, off);
    lcnt += __shfl_down(lcnt, off);
  }
  __shared__ float rs[4], rc[4];
  if (lane == 0) { rs[w] = lsum; rc[w] = lcnt; }
  __syncthreads();
  if (tid == 0) {
    atomicAdd(&accum[0], rs[0] + rs[1] + rs[2] + rs[3]);
    atomicAdd(&accum[1], rc[0] + rc[1] + rc[2] + rc[3]);
  }
}

// ---------------------------------------------------------------------------
// Fallback (tiny workspace): bf16 on-the-fly convert, 256 threads / 4 waves,
// single-buffer, BK=64 bf16 (verified R2 structure), 128x128 tiles.
// ---------------------------------------------------------------------------
__global__ __launch_bounds__(256) void tri_gemm_fly(const float* __restrict__ inF,
                                                    const float* __restrict__ invn,
                                                    float* __restrict__ accum) {
  enum { FBK = 64 };
  int t = blockIdx.x, bi = 0;
  while (t >= NB - bi) { t -= NB - bi; ++bi; }
  const int bj = bi + t;

  __shared__ __align__(16) ushort Asm[BT * FBK];
  __shared__ __align__(16) ushort Bsm[BT * FBK];

  const int tid  = threadIdx.x;
  const int lane = tid & 63;
  const int w    = tid >> 6;
  const int wr   = w >> 1, wc = w & 1;

  f32x4 acc[4][4] = {};
  const int rowA = bi * BT, rowB = bj * BT;

  for (int k0 = 0; k0 < DIM; k0 += FBK) {
    if (k0) __syncthreads();
    #pragma unroll
    for (int p = 0; p < 8; ++p) {
      int c   = p * 256 + tid;
      int isB = c >> 10;
      int cc  = c & 1023;
      int r   = cc >> 3;
      int s   = cc & 7;
      const int grow = (isB ? rowB : rowA) + r;
      const float4* src = (const float4*)(inF + (size_t)grow * DIM + k0 + s * 8);
      float4 v0 = src[0], v1 = src[1];
      int4 pack;
      ushort* h = (ushort*)&pack;
      h[0] = f32_to_bf16(v0.x); h[1] = f32_to_bf16(v0.y);
      h[2] = f32_to_bf16(v0.z); h[3] = f32_to_bf16(v0.w);
      h[4] = f32_to_bf16(v1.x); h[5] = f32_to_bf16(v1.y);
      h[6] = f32_to_bf16(v1.z); h[7] = f32_to_bf16(v1.w);
      *(int4*)((isB ? Bsm : Asm) + r * FBK + (s ^ (r & 7)) * 8) = pack;
    }
    __syncthreads();

    s16x8 af[2][4], bfv[2][4];
    const int fr = lane & 15, hi = lane >> 4;
    #pragma unroll
    for (int kk = 0; kk < 2; ++kk)
      #pragma unroll
      for (int m = 0; m < 4; ++m) {
        const int ra = wr * 64 + m * 16 + fr;
        af[kk][m] = *(const s16x8*)(Asm + ra * FBK + ((kk * 4 + hi) ^ (ra & 7)) * 8);
        const int rb = wc * 64 + m * 16 + fr;
        bfv[kk][m] = *(const s16x8*)(Bsm + rb * FBK + ((kk * 4 + hi) ^ (rb & 7)) * 8);
      }
    #pragma unroll
    for (int kk = 0; kk < 2; ++kk)
      #pragma unroll
      for (int m = 0; m < 4; ++m)
        #pragma unroll
        for (int n = 0; n < 4; ++n)
          acc[m][n] = __builtin_amdgcn_mfma_f32_16x16x32_bf16(af[kk][m], bfv[kk][n],
                                                              acc[m][n], 0, 0, 0);
  }

  float lsum = 0.f, lcnt = 0.f;
  const int gib = rowA + wr * 64;
  const int gjb = rowB + wc * 64;
  #pragma unroll
  for (int m = 0; m < 4; ++m)
    #pragma unroll
    for (int n = 0; n < 4; ++n)
      #pragma unroll
      for (int r = 0; r < 4; ++r) {
        int gi = gib + m * 16 + (lane >> 4) * 4 + r;
        int gj = gjb + n * 16 + (lane & 15);
        float s = acc[m][n][r] * invn[gi] * invn[gj];
        if (gi < gj && s > MARGIN) { lsum += s - MARGIN; lcnt += 1.f; }
      }
  #pragma unroll
  for (int off = 32; off; off >>= 1) {
    lsum += __shfl_down(lsum, off);
    lcnt += __shfl_down(lcnt, off);
  }
  __shared__ float rs[4], rc[4];
  if (lane == 0) { rs[w] = lsum; rc[w] = lcnt; }
  __syncthreads();
  if (tid == 0) {
    atomicAdd(&accum[0], rs[0] + rs[1] + rs[2] + rs[3]);
    atomicAdd(&accum[1], rc[0] + rc[1] + rc[2] + rc[3]);
  }
}

__global__ void finalize_kernel(const float* __restrict__ accum, float* __restrict__ out) {
  if (threadIdx.x == 0) out[0] = (accum[1] < 0.5f) ? 0.0f : accum[0] / accum[1];
}

extern "C" void kernel_launch(void* const* d_in, const int* in_sizes, int n_in,
                              void* d_out, int out_size, void* d_ws, size_t ws_size,
                              hipStream_t stream) {
  const float* in = (const float*)d_in[0];
  float* out = (float*)d_out;
  const size_t pn_bytes = (size_t)NROWS * ROWB;   // fp4: 4.2 MB

  if (ws_size >= pn_bytes + 2 * sizeof(float)) {
    unsigned char* pn = (unsigned char*)d_ws;
    float* accum = (float*)((char*)d_ws + pn_bytes);
    prep_kernel<0><<<NROWS, 256, 0, stream>>>(in, pn, nullptr, accum);
    tri_gemm<<<NBLK, 256, 0, stream>>>(pn, accum);
    finalize_kernel<<<1, 64, 0, stream>>>(accum, out);
  } else {
    float* invn  = (float*)d_ws;
    float* accum = (float*)((char*)d_ws + NROWS * sizeof(float));
    prep_kernel<1><<<NROWS, 256, 0, stream>>>(in, nullptr, invn, accum);
    tri_gemm_fly<<<NBLK, 256, 0, stream>>>(in, invn, accum);
    finalize_kernel<<<1, 64, 0, stream>>>(accum, out);
  }
}